// Round 8
// baseline (393.414 us; speedup 1.0000x reference)
//
#include <hip/hip_runtime.h>
#include <hip/hip_bf16.h>
#include <hip/hip_fp16.h>

#define D 128
#define CAP 64   // padded CSR slot capacity; P(deg>=64)~1e-16 for Poisson(16)

typedef _Float16 half8 __attribute__((ext_vector_type(8)));
typedef _Float16 half4 __attribute__((ext_vector_type(4)));
typedef float f32x4 __attribute__((ext_vector_type(4)));

// ============ W prep: WT[n][k] = (fp16) W[k][n], both weights ============

__global__ void k_prepW2(const float* __restrict__ W1, const float* __restrict__ W2,
                         _Float16* __restrict__ WT1, _Float16* __restrict__ WT2) {
    const int i = blockIdx.x * 256 + threadIdx.x;
    if (i < 2 * D * D) {
        const float* W = (i < D * D) ? W1 : W2;
        _Float16* WT   = (i < D * D) ? WT1 : WT2;
        const int j = (i < D * D) ? i : i - D * D;
        const int k = j >> 7, n = j & 127;
        WT[n * D + k] = (_Float16)W[j];
    }
}

// ============ GEMM body (A from global), fp16 out ============

template <typename AT>
__device__ __forceinline__ void gemm_body(int bid, const AT* __restrict__ A,
                                          const _Float16* __restrict__ WT,
                                          _Float16* __restrict__ Hout, int nrows) {
    const int wv   = threadIdx.x >> 6;
    const int lane = threadIdx.x & 63;
    const int l    = lane & 15;
    const int quad = lane >> 4;
    const int base = bid * 64 + wv * 16;
    int row = base + l;
    const bool valid = row < nrows;
    if (!valid) row = nrows - 1;

    half8 af[4];
    const AT* Ar = &A[(size_t)row * D + quad * 8];
    #pragma unroll
    for (int s = 0; s < 4; ++s) {
        if constexpr (sizeof(AT) == 4) {
            const float4 v0 = *(const float4*)(Ar + s * 32);
            const float4 v1 = *(const float4*)(Ar + s * 32 + 4);
            af[s][0] = (_Float16)v0.x; af[s][1] = (_Float16)v0.y;
            af[s][2] = (_Float16)v0.z; af[s][3] = (_Float16)v0.w;
            af[s][4] = (_Float16)v1.x; af[s][5] = (_Float16)v1.y;
            af[s][6] = (_Float16)v1.z; af[s][7] = (_Float16)v1.w;
        } else {
            af[s] = *(const half8*)(Ar + s * 32);
        }
    }

    f32x4 acc[8];
    #pragma unroll
    for (int t = 0; t < 8; ++t) acc[t] = (f32x4)0.0f;

    #pragma unroll
    for (int s = 0; s < 4; ++s) {
        #pragma unroll
        for (int t = 0; t < 8; ++t) {
            const half8 wf = *(const half8*)&WT[(size_t)(t * 16 + l) * D + s * 32 + quad * 8];
            acc[t] = __builtin_amdgcn_mfma_f32_16x16x32_f16(wf, af[s], acc[t], 0, 0, 0);
        }
    }

    if (valid) {
        _Float16* Or = &Hout[(size_t)row * D + quad * 4];
        #pragma unroll
        for (int t = 0; t < 8; ++t) {
            half4 o;
            o[0] = (_Float16)acc[t][0]; o[1] = (_Float16)acc[t][1];
            o[2] = (_Float16)acc[t][2]; o[3] = (_Float16)acc[t][3];
            *(half4*)(Or + t * 16) = o;
        }
    }
}

// ============ fused: GEMM1 ∥ hist + padded-CSR scatter ============
// Edge path = round-0 form verbatim: 1 edge/thread, device-scope atomic,
// fp16 hA (proven 109±1 us; fp32-hA cost +50 us in r6; 4/thread = variance
// r2; XCD-private scope null-to-negative r4). GEMM blocks first so the
// scatter trickles in behind them (r1: edge-first serialized, +74 us).

__launch_bounds__(256)
__global__ void k_fused1(const int* __restrict__ src, const int* __restrict__ dst,
                         int* __restrict__ cnt, int* __restrict__ ep, int E, int gblocks,
                         const float* __restrict__ A, const _Float16* __restrict__ WT,
                         _Float16* __restrict__ Hout, int nrows) {
    if ((int)blockIdx.x < gblocks) {
        gemm_body<float>((int)blockIdx.x, A, WT, Hout, nrows);
        return;
    }
    const int i = ((int)blockIdx.x - gblocks) * 256 + threadIdx.x;
    if (i < E) {
        const int d = dst[i];
        const int r = atomicAdd(&cnt[d], 1);
        if (r < CAP) ep[(size_t)d * CAP + r] = src[i];
    }
}

// ============ k_pack: embed cnt[src] into ep entries ============
// After the histogram is final: ep[slot] = src | (min(cnt[src],4095) << 20).
// src < 2^17; graph cnt max ~60 so the clamp is never active here.
// This turns the agg's per-edge dependent cnt[sv] GATHER (the r6-confirmed
// bottleneck) into a VALU extract+rsqrt — no extra rounding anywhere.
// cnt table is L2-resident (400 KB); ~10 us.

__launch_bounds__(256)
__global__ void k_pack(int* __restrict__ ep, const int* __restrict__ cnt, int n) {
    const int i = blockIdx.x * 256 + threadIdx.x;   // slot index
    const int row = i >> 6;                         // CAP = 64
    if (row >= n) return;
    const int j = i & 63;
    const int deg = min(cnt[row], CAP);
    if (j < deg) {
        const unsigned pv = (unsigned)ep[i];
        const unsigned cs = (unsigned)min(cnt[pv], 4095);
        ep[i] = (int)(pv | (cs << 20));
    }
}

// ============ agg row: packed-weight gather+FMA, r6 loop shape ============
// w = rsqrt(1 + packed_cnt) * dd computed in exact f32 from exact integer
// counts -> bit-identical numerics to the r2-proven path. Chain per chunk:
// ep load -> VALU (extract+rsqrt) -> dual shfl -> gathers. One memory
// round-trip shorter than r0-r2; no pre-scaled g buffers (r6's cost).

template <int U>
__device__ __forceinline__ void grp(const _Float16* __restrict__ h, int c4,
                                    int sv, float wl, int k, float4& acc) {
    int s[U]; float w[U]; half4 v[U];
    #pragma unroll
    for (int u = 0; u < U; ++u) {
        s[u] = __shfl(sv, k + u, 32);
        w[u] = __shfl(wl, k + u, 32);
    }
    #pragma unroll
    for (int u = 0; u < U; ++u)
        v[u] = *(const half4*)&h[(size_t)s[u] * D + c4];
    #pragma unroll
    for (int u = 0; u < U; ++u) {
        acc.x = fmaf((float)v[u][0], w[u], acc.x);
        acc.y = fmaf((float)v[u][1], w[u], acc.y);
        acc.z = fmaf((float)v[u][2], w[u], acc.z);
        acc.w = fmaf((float)v[u][3], w[u], acc.w);
    }
}

__device__ __forceinline__ float4 agg_row(const _Float16* __restrict__ h,
                                          const int* __restrict__ cnt,
                                          const unsigned* __restrict__ ep,
                                          int row, int lane) {
    const int c4 = lane * 4;
    const int cr = cnt[row];
    const float dd = rsqrtf(1.0f + (float)cr);
    const float sw = dd * dd;
    const half4 hv = *(const half4*)&h[(size_t)row * D + c4];
    float4 acc = make_float4((float)hv[0] * sw, (float)hv[1] * sw,
                             (float)hv[2] * sw, (float)hv[3] * sw);
    const int deg = min(cr, CAP);
    const size_t base = (size_t)row * CAP;

    for (int c = 0; c < deg; c += 32) {
        unsigned pv = 0;
        if (c + lane < deg) pv = ep[base + c + lane];
        const int   sv = (int)(pv & 0xFFFFFu);
        const float wl = rsqrtf(1.0f + (float)(pv >> 20)) * dd;
        const int m = min(32, deg - c);
        int k = 0;
        for (; k + 8 <= m; k += 8) grp<8>(h, c4, sv, wl, k, acc);
        for (; k + 4 <= m; k += 4) grp<4>(h, c4, sv, wl, k, acc);
        for (; k < m; ++k)         grp<1>(h, c4, sv, wl, k, acc);
    }
    return acc;
}

// ============ fused agg(layer1) + GEMM2: 32 rows / 128 threads ============

#define LSTRIDE 136  // _Float16 units (272 B row stride, 16B-aligned)

__launch_bounds__(128)
__global__ void k_agg_gemm2(const _Float16* __restrict__ h, const int* __restrict__ cnt,
                            const unsigned* __restrict__ ep, const float* __restrict__ bias,
                            const _Float16* __restrict__ WT,
                            _Float16* __restrict__ Hout, int n) {
    __shared__ _Float16 sh[32 * LSTRIDE];

    const int r0   = blockIdx.x * 32;
    const int hw   = threadIdx.x >> 5;   // 0..3
    const int lane = threadIdx.x & 31;
    const int c4   = lane * 4;
    const float4 bb = *(const float4*)&bias[c4];

    #pragma unroll 1
    for (int i = 0; i < 8; ++i) {
        const int rl  = hw * 8 + i;
        const int row = r0 + rl;
        half4 o;
        if (row < n) {
            float4 acc = agg_row(h, cnt, ep, row, lane);
            o[0] = (_Float16)fmaxf(acc.x + bb.x, 0.f);
            o[1] = (_Float16)fmaxf(acc.y + bb.y, 0.f);
            o[2] = (_Float16)fmaxf(acc.z + bb.z, 0.f);
            o[3] = (_Float16)fmaxf(acc.w + bb.w, 0.f);
        } else {
            o[0] = o[1] = o[2] = o[3] = (_Float16)0.f;
        }
        *(half4*)&sh[rl * LSTRIDE + c4] = o;
    }
    __syncthreads();

    const int wv   = threadIdx.x >> 6;   // 0..1
    const int wl64 = threadIdx.x & 63;
    const int l    = wl64 & 15;
    const int quad = wl64 >> 4;
    const int rl   = wv * 16 + l;
    const int row  = r0 + rl;

    half8 af[4];
    #pragma unroll
    for (int s = 0; s < 4; ++s)
        af[s] = *(const half8*)&sh[rl * LSTRIDE + s * 32 + quad * 8];

    f32x4 acc[8];
    #pragma unroll
    for (int t = 0; t < 8; ++t) acc[t] = (f32x4)0.0f;

    #pragma unroll
    for (int s = 0; s < 4; ++s) {
        #pragma unroll
        for (int t = 0; t < 8; ++t) {
            const half8 wf = *(const half8*)&WT[(size_t)(t * 16 + l) * D + s * 32 + quad * 8];
            acc[t] = __builtin_amdgcn_mfma_f32_16x16x32_f16(wf, af[s], acc[t], 0, 0, 0);
        }
    }

    if (row < n) {
        _Float16* Or = &Hout[(size_t)row * D + quad * 4];
        #pragma unroll
        for (int t = 0; t < 8; ++t) {
            half4 o;
            o[0] = (_Float16)acc[t][0]; o[1] = (_Float16)acc[t][1];
            o[2] = (_Float16)acc[t][2]; o[3] = (_Float16)acc[t][3];
            *(half4*)(Or + t * 16) = o;
        }
    }
}

// ============ final agg (layer2) -> fp32 d_out: 8 rows / 256 thr ============

__launch_bounds__(256)
__global__ void k_agg_out(const _Float16* __restrict__ h, const int* __restrict__ cnt,
                          const unsigned* __restrict__ ep, const float* __restrict__ bias,
                          float* __restrict__ out, int n) {
    const int row = blockIdx.x * 8 + (threadIdx.x >> 5);
    if (row >= n) return;
    const int lane = threadIdx.x & 31;
    const int c4 = lane * 4;
    const float4 bb = *(const float4*)&bias[c4];

    float4 acc = agg_row(h, cnt, ep, row, lane);
    acc.x = fmaxf(acc.x + bb.x, 0.f);
    acc.y = fmaxf(acc.y + bb.y, 0.f);
    acc.z = fmaxf(acc.z + bb.z, 0.f);
    acc.w = fmaxf(acc.w + bb.w, 0.f);
    *(float4*)&out[(size_t)row * D + c4] = acc;
}

// ================= launch =================

extern "C" void kernel_launch(void* const* d_in, const int* in_sizes, int n_in,
                              void* d_out, int out_size, void* d_ws, size_t ws_size,
                              hipStream_t stream) {
    const float* x  = (const float*)d_in[0];
    const int*   ei = (const int*)d_in[1];
    const float* W1 = (const float*)d_in[2];
    const float* b1 = (const float*)d_in[3];
    const float* W2 = (const float*)d_in[4];
    const float* b2 = (const float*)d_in[5];

    const int N = in_sizes[0] / D;     // 100000
    const int E = in_sizes[1] / 2;     // 1600000
    const int* src = ei;
    const int* dst = ei + E;
    float* out = (float*)d_out;

    auto align256 = [](size_t v) { return (v + 255) & ~(size_t)255; };
    char* w = (char*)d_ws;
    int*      cnt = (int*)w;      w += align256((size_t)N * 4);
    _Float16* WT1 = (_Float16*)w; w += align256((size_t)D * D * 2);
    _Float16* WT2 = (_Float16*)w; w += align256((size_t)D * D * 2);
    int*      ep  = (int*)w;      w += align256((size_t)N * CAP * 4);
    _Float16* hA  = (_Float16*)w; w += align256((size_t)N * D * 2);
    _Float16* hB  = (_Float16*)w;

    const int egrid = (E + 255) / 256;     // 6250 edge blocks (1 edge/thread, r0-proven)
    const int ggrid = (N + 63) / 64;       // 1563 GEMM blocks

    hipMemsetAsync(cnt, 0, (size_t)N * 4, stream);
    k_prepW2<<<(2 * D * D + 255) / 256, 256, 0, stream>>>(W1, W2, WT1, WT2);

    // GEMM1 (-> fp16 hA) first, edge scatter trickles in behind (overlap)
    k_fused1<<<ggrid + egrid, 256, 0, stream>>>(src, dst, cnt, ep, E, ggrid, x, WT1, hA, N);

    // embed cnt[src] into ep entries (~10us; kills the per-edge dependent gather)
    k_pack<<<(N * CAP + 255) / 256, 256, 0, stream>>>(ep, cnt, N);

    // agg(layer1) + GEMM2 fused, 32 rows/block
    k_agg_gemm2<<<(N + 31) / 32, 128, 0, stream>>>(hA, cnt, (const unsigned*)ep, b1, WT2, hB, N);

    // final aggregation -> d_out
    k_agg_out<<<(N + 7) / 8, 256, 0, stream>>>(hB, cnt, (const unsigned*)ep, b2, out, N);
}

// Round 9
// 373.981 us; speedup vs baseline: 1.0520x; 1.0520x over previous
//
#include <hip/hip_runtime.h>
#include <hip/hip_bf16.h>
#include <hip/hip_fp16.h>

#define D 128
#define CAPM 32   // main slots/node (128B hot region; P(deg>32)~1.2e-4)
#define CAPT 64   // total slots incl. overflow region; P(deg>64)~1e-16

typedef _Float16 half8 __attribute__((ext_vector_type(8)));
typedef _Float16 half4 __attribute__((ext_vector_type(4)));
typedef float f32x4 __attribute__((ext_vector_type(4)));

// ============ W prep: WT[n][k] = (fp16) W[k][n], both weights ============

__global__ void k_prepW2(const float* __restrict__ W1, const float* __restrict__ W2,
                         _Float16* __restrict__ WT1, _Float16* __restrict__ WT2) {
    const int i = blockIdx.x * 256 + threadIdx.x;
    if (i < 2 * D * D) {
        const float* W = (i < D * D) ? W1 : W2;
        _Float16* WT   = (i < D * D) ? WT1 : WT2;
        const int j = (i < D * D) ? i : i - D * D;
        const int k = j >> 7, n = j & 127;
        WT[n * D + k] = (_Float16)W[j];
    }
}

// ============ GEMM body (A from global), fp16 out ============

template <typename AT>
__device__ __forceinline__ void gemm_body(int bid, const AT* __restrict__ A,
                                          const _Float16* __restrict__ WT,
                                          _Float16* __restrict__ Hout, int nrows) {
    const int wv   = threadIdx.x >> 6;
    const int lane = threadIdx.x & 63;
    const int l    = lane & 15;
    const int quad = lane >> 4;
    const int base = bid * 64 + wv * 16;
    int row = base + l;
    const bool valid = row < nrows;
    if (!valid) row = nrows - 1;

    half8 af[4];
    const AT* Ar = &A[(size_t)row * D + quad * 8];
    #pragma unroll
    for (int s = 0; s < 4; ++s) {
        if constexpr (sizeof(AT) == 4) {
            const float4 v0 = *(const float4*)(Ar + s * 32);
            const float4 v1 = *(const float4*)(Ar + s * 32 + 4);
            af[s][0] = (_Float16)v0.x; af[s][1] = (_Float16)v0.y;
            af[s][2] = (_Float16)v0.z; af[s][3] = (_Float16)v0.w;
            af[s][4] = (_Float16)v1.x; af[s][5] = (_Float16)v1.y;
            af[s][6] = (_Float16)v1.z; af[s][7] = (_Float16)v1.w;
        } else {
            af[s] = *(const half8*)(Ar + s * 32);
        }
    }

    f32x4 acc[8];
    #pragma unroll
    for (int t = 0; t < 8; ++t) acc[t] = (f32x4)0.0f;

    #pragma unroll
    for (int s = 0; s < 4; ++s) {
        #pragma unroll
        for (int t = 0; t < 8; ++t) {
            const half8 wf = *(const half8*)&WT[(size_t)(t * 16 + l) * D + s * 32 + quad * 8];
            acc[t] = __builtin_amdgcn_mfma_f32_16x16x32_f16(wf, af[s], acc[t], 0, 0, 0);
        }
    }

    if (valid) {
        _Float16* Or = &Hout[(size_t)row * D + quad * 4];
        #pragma unroll
        for (int t = 0; t < 8; ++t) {
            half4 o;
            o[0] = (_Float16)acc[t][0]; o[1] = (_Float16)acc[t][1];
            o[2] = (_Float16)acc[t][2]; o[3] = (_Float16)acc[t][3];
            *(half4*)(Or + t * 16) = o;
        }
    }
}

// ============ fused: GEMM1 ∥ hist + split padded-CSR scatter ============
// Edge scatter: 1 edge/thread, device-scope atomic (r0-proven form) BUT the
// per-node hot region shrinks 256B -> 128B (CAPM=32): scattered 4B stores
// dirty half the lines. Theory (r8): the edge wall is partial-line RMW
// traffic (WRITE_SIZE 122MB ~ 2.2TB/s effective); falsifier = WRITE_SIZE,
// which is machine-variance-immune. Overflow (P~1.2e-4/node) goes to a
// separate 32-slot region; beyond 64 drops (P~1e-16, as all prior rounds).

__launch_bounds__(256)
__global__ void k_fused1(const int* __restrict__ src, const int* __restrict__ dst,
                         int* __restrict__ cnt, int* __restrict__ ep, int* __restrict__ epo,
                         int E, int gblocks,
                         const float* __restrict__ A, const _Float16* __restrict__ WT,
                         _Float16* __restrict__ Hout, int nrows) {
    if ((int)blockIdx.x < gblocks) {
        gemm_body<float>((int)blockIdx.x, A, WT, Hout, nrows);
        return;
    }
    const int i = ((int)blockIdx.x - gblocks) * 256 + threadIdx.x;
    if (i < E) {
        const int d = dst[i];
        const int r = atomicAdd(&cnt[d], 1);
        if (r < CAPM)       ep [(size_t)(d << 5) + r]          = src[i];
        else if (r < CAPT)  epo[(size_t)(d << 5) + (r - CAPM)] = src[i];
    }
}

// ============ k_pack: embed cnt[src] into slot entries ============
// slot value := src | (min(cnt[src],4095) << 20). src < 2^17, bits 17-19
// zero, mask 0xFFFFF recovers src exactly; weights later computed in exact
// f32 from exact integer counts -> bit-identical numerics to r0/r2 path.
// Kills the per-edge dependent cnt[sv] gather in the agg critical chain.

__launch_bounds__(256)
__global__ void k_pack(int* __restrict__ ep, int* __restrict__ epo,
                       const int* __restrict__ cnt, int n) {
    const int i = blockIdx.x * 256 + threadIdx.x;   // logical slot index, 64/node
    const int row = i >> 6;
    if (row >= n) return;
    const int j = i & 63;
    const int deg = min(cnt[row], CAPT);
    if (j < deg) {
        int* p = (j < CAPM) ? &ep[(size_t)(row << 5) + j]
                            : &epo[(size_t)(row << 5) + (j - CAPM)];
        const unsigned pv = (unsigned)*p;
        *p = (int)(pv | ((unsigned)min(cnt[pv], 4095) << 20));
    }
}

// ============ agg row: single-shfl packed gather+FMA ============
// Per neighbor: ONE shfl of the packed word; gather address = pv & 0xFFFFF
// issues right after shfl+AND; the rsqrt weight computes under the gather's
// memory latency. Combines r6's single-shfl loop shape (the proven agg win)
// with exact packed weights (no pre-scale buffers, no extra rounding).

template <int U>
__device__ __forceinline__ void grp(const _Float16* __restrict__ h, int c4,
                                    unsigned pv, float dd, int k, float4& acc) {
    unsigned p[U]; half4 v[U];
    #pragma unroll
    for (int u = 0; u < U; ++u) p[u] = __shfl(pv, k + u, 32);
    #pragma unroll
    for (int u = 0; u < U; ++u)
        v[u] = *(const half4*)&h[(size_t)(p[u] & 0xFFFFFu) * D + c4];
    #pragma unroll
    for (int u = 0; u < U; ++u) {
        const float w = rsqrtf(1.0f + (float)(p[u] >> 20)) * dd;
        acc.x = fmaf((float)v[u][0], w, acc.x);
        acc.y = fmaf((float)v[u][1], w, acc.y);
        acc.z = fmaf((float)v[u][2], w, acc.z);
        acc.w = fmaf((float)v[u][3], w, acc.w);
    }
}

__device__ __forceinline__ float4 agg_row(const _Float16* __restrict__ h,
                                          const int* __restrict__ cnt,
                                          const unsigned* __restrict__ ep,
                                          const unsigned* __restrict__ epo,
                                          int row, int lane) {
    const int c4 = lane * 4;
    const int cr = cnt[row];
    const float dd = rsqrtf(1.0f + (float)cr);
    const float sw = dd * dd;
    const half4 hv = *(const half4*)&h[(size_t)row * D + c4];
    float4 acc = make_float4((float)hv[0] * sw, (float)hv[1] * sw,
                             (float)hv[2] * sw, (float)hv[3] * sw);
    const int deg = min(cr, CAPT);

    for (int c = 0; c < deg; c += 32) {
        const unsigned* b = (c == 0) ? &ep[(size_t)(row << 5)] : &epo[(size_t)(row << 5)];
        unsigned pv = 0;
        if (c + lane < deg) pv = b[lane];
        const int m = min(32, deg - c);
        int k = 0;
        for (; k + 8 <= m; k += 8) grp<8>(h, c4, pv, dd, k, acc);
        for (; k + 4 <= m; k += 4) grp<4>(h, c4, pv, dd, k, acc);
        for (; k < m; ++k)         grp<1>(h, c4, pv, dd, k, acc);
    }
    return acc;
}

// ============ fused agg(layer1) + GEMM2: 32 rows / 128 threads ============

#define LSTRIDE 136  // _Float16 units (272 B row stride, 16B-aligned)

__launch_bounds__(128)
__global__ void k_agg_gemm2(const _Float16* __restrict__ h, const int* __restrict__ cnt,
                            const unsigned* __restrict__ ep, const unsigned* __restrict__ epo,
                            const float* __restrict__ bias, const _Float16* __restrict__ WT,
                            _Float16* __restrict__ Hout, int n) {
    __shared__ _Float16 sh[32 * LSTRIDE];

    const int r0   = blockIdx.x * 32;
    const int hw   = threadIdx.x >> 5;   // 0..3
    const int lane = threadIdx.x & 31;
    const int c4   = lane * 4;
    const float4 bb = *(const float4*)&bias[c4];

    #pragma unroll 1
    for (int i = 0; i < 8; ++i) {
        const int rl  = hw * 8 + i;
        const int row = r0 + rl;
        half4 o;
        if (row < n) {
            float4 acc = agg_row(h, cnt, ep, epo, row, lane);
            o[0] = (_Float16)fmaxf(acc.x + bb.x, 0.f);
            o[1] = (_Float16)fmaxf(acc.y + bb.y, 0.f);
            o[2] = (_Float16)fmaxf(acc.z + bb.z, 0.f);
            o[3] = (_Float16)fmaxf(acc.w + bb.w, 0.f);
        } else {
            o[0] = o[1] = o[2] = o[3] = (_Float16)0.f;
        }
        *(half4*)&sh[rl * LSTRIDE + c4] = o;
    }
    __syncthreads();

    const int wv   = threadIdx.x >> 6;   // 0..1
    const int wl64 = threadIdx.x & 63;
    const int l    = wl64 & 15;
    const int quad = wl64 >> 4;
    const int rl   = wv * 16 + l;
    const int row  = r0 + rl;

    half8 af[4];
    #pragma unroll
    for (int s = 0; s < 4; ++s)
        af[s] = *(const half8*)&sh[rl * LSTRIDE + s * 32 + quad * 8];

    f32x4 acc[8];
    #pragma unroll
    for (int t = 0; t < 8; ++t) acc[t] = (f32x4)0.0f;

    #pragma unroll
    for (int s = 0; s < 4; ++s) {
        #pragma unroll
        for (int t = 0; t < 8; ++t) {
            const half8 wf = *(const half8*)&WT[(size_t)(t * 16 + l) * D + s * 32 + quad * 8];
            acc[t] = __builtin_amdgcn_mfma_f32_16x16x32_f16(wf, af[s], acc[t], 0, 0, 0);
        }
    }

    if (row < n) {
        _Float16* Or = &Hout[(size_t)row * D + quad * 4];
        #pragma unroll
        for (int t = 0; t < 8; ++t) {
            half4 o;
            o[0] = (_Float16)acc[t][0]; o[1] = (_Float16)acc[t][1];
            o[2] = (_Float16)acc[t][2]; o[3] = (_Float16)acc[t][3];
            *(half4*)(Or + t * 16) = o;
        }
    }
}

// ============ final agg (layer2) -> fp32 d_out: 8 rows / 256 thr ============

__launch_bounds__(256)
__global__ void k_agg_out(const _Float16* __restrict__ h, const int* __restrict__ cnt,
                          const unsigned* __restrict__ ep, const unsigned* __restrict__ epo,
                          const float* __restrict__ bias, float* __restrict__ out, int n) {
    const int row = blockIdx.x * 8 + (threadIdx.x >> 5);
    if (row >= n) return;
    const int lane = threadIdx.x & 31;
    const int c4 = lane * 4;
    const float4 bb = *(const float4*)&bias[c4];

    float4 acc = agg_row(h, cnt, ep, epo, row, lane);
    acc.x = fmaxf(acc.x + bb.x, 0.f);
    acc.y = fmaxf(acc.y + bb.y, 0.f);
    acc.z = fmaxf(acc.z + bb.z, 0.f);
    acc.w = fmaxf(acc.w + bb.w, 0.f);
    *(float4*)&out[(size_t)row * D + c4] = acc;
}

// ================= launch =================

extern "C" void kernel_launch(void* const* d_in, const int* in_sizes, int n_in,
                              void* d_out, int out_size, void* d_ws, size_t ws_size,
                              hipStream_t stream) {
    const float* x  = (const float*)d_in[0];
    const int*   ei = (const int*)d_in[1];
    const float* W1 = (const float*)d_in[2];
    const float* b1 = (const float*)d_in[3];
    const float* W2 = (const float*)d_in[4];
    const float* b2 = (const float*)d_in[5];

    const int N = in_sizes[0] / D;     // 100000
    const int E = in_sizes[1] / 2;     // 1600000
    const int* src = ei;
    const int* dst = ei + E;
    float* out = (float*)d_out;

    auto align256 = [](size_t v) { return (v + 255) & ~(size_t)255; };
    char* w = (char*)d_ws;
    int*      cnt = (int*)w;      w += align256((size_t)N * 4);
    _Float16* WT1 = (_Float16*)w; w += align256((size_t)D * D * 2);
    _Float16* WT2 = (_Float16*)w; w += align256((size_t)D * D * 2);
    int*      ep  = (int*)w;      w += align256((size_t)N * CAPM * 4);   // 12.8 MB
    int*      epo = (int*)w;      w += align256((size_t)N * CAPM * 4);   // 12.8 MB
    _Float16* hA  = (_Float16*)w; w += align256((size_t)N * D * 2);
    _Float16* hB  = (_Float16*)w;
    // total ~77.3 MB — same proven footprint as r0/r2/r5

    const int egrid = (E + 255) / 256;     // 6250 edge blocks (1 edge/thread)
    const int ggrid = (N + 63) / 64;       // 1563 GEMM blocks

    hipMemsetAsync(cnt, 0, (size_t)N * 4, stream);
    k_prepW2<<<(2 * D * D + 255) / 256, 256, 0, stream>>>(W1, W2, WT1, WT2);

    // GEMM1 (-> fp16 hA) first, edge scatter trickles in behind (overlap)
    k_fused1<<<ggrid + egrid, 256, 0, stream>>>(src, dst, cnt, ep, epo, E, ggrid,
                                                x, WT1, hA, N);

    // embed cnt[src] into slot entries (~10us)
    k_pack<<<(N * CAPT + 255) / 256, 256, 0, stream>>>(ep, epo, cnt, N);

    // agg(layer1) + GEMM2 fused, 32 rows/block
    k_agg_gemm2<<<(N + 31) / 32, 128, 0, stream>>>(hA, cnt, (const unsigned*)ep,
                                                   (const unsigned*)epo, b1, WT2, hB, N);

    // final aggregation -> d_out
    k_agg_out<<<(N + 7) / 8, 256, 0, stream>>>(hB, cnt, (const unsigned*)ep,
                                               (const unsigned*)epo, b2, out, N);
}

// Round 10
// 338.048 us; speedup vs baseline: 1.1638x; 1.1063x over previous
//
#include <hip/hip_runtime.h>
#include <hip/hip_bf16.h>
#include <hip/hip_fp16.h>

#define D 128
#define EPB 4096      // edges per phase-A block (256 thr x 16)
#define NBMAX 784     // max coarse bins (ceil(100000/128)=782)
#define BCAP 2560     // per-coarse-bin capacity: Poisson(2048) + 11 sigma

typedef _Float16 half8 __attribute__((ext_vector_type(8)));
typedef _Float16 half4 __attribute__((ext_vector_type(4)));
typedef float f32x4 __attribute__((ext_vector_type(4)));

// ============ W prep: WT[n][k] = (fp16) W[k][n], both weights ============

__global__ void k_prepW2(const float* __restrict__ W1, const float* __restrict__ W2,
                         _Float16* __restrict__ WT1, _Float16* __restrict__ WT2) {
    const int i = blockIdx.x * 256 + threadIdx.x;
    if (i < 2 * D * D) {
        const float* W = (i < D * D) ? W1 : W2;
        _Float16* WT   = (i < D * D) ? WT1 : WT2;
        const int j = (i < D * D) ? i : i - D * D;
        const int k = j >> 7, n = j & 127;
        WT[n * D + k] = (_Float16)W[j];
    }
}

// ============ GEMM body (A from global), fp16 out ============

template <typename AT>
__device__ __forceinline__ void gemm_body(int bid, const AT* __restrict__ A,
                                          const _Float16* __restrict__ WT,
                                          _Float16* __restrict__ Hout, int nrows) {
    const int wv   = threadIdx.x >> 6;
    const int lane = threadIdx.x & 63;
    const int l    = lane & 15;
    const int quad = lane >> 4;
    const int base = bid * 64 + wv * 16;
    int row = base + l;
    const bool valid = row < nrows;
    if (!valid) row = nrows - 1;

    half8 af[4];
    const AT* Ar = &A[(size_t)row * D + quad * 8];
    #pragma unroll
    for (int s = 0; s < 4; ++s) {
        if constexpr (sizeof(AT) == 4) {
            const float4 v0 = *(const float4*)(Ar + s * 32);
            const float4 v1 = *(const float4*)(Ar + s * 32 + 4);
            af[s][0] = (_Float16)v0.x; af[s][1] = (_Float16)v0.y;
            af[s][2] = (_Float16)v0.z; af[s][3] = (_Float16)v0.w;
            af[s][4] = (_Float16)v1.x; af[s][5] = (_Float16)v1.y;
            af[s][6] = (_Float16)v1.z; af[s][7] = (_Float16)v1.w;
        } else {
            af[s] = *(const half8*)(Ar + s * 32);
        }
    }

    f32x4 acc[8];
    #pragma unroll
    for (int t = 0; t < 8; ++t) acc[t] = (f32x4)0.0f;

    #pragma unroll
    for (int s = 0; s < 4; ++s) {
        #pragma unroll
        for (int t = 0; t < 8; ++t) {
            const half8 wf = *(const half8*)&WT[(size_t)(t * 16 + l) * D + s * 32 + quad * 8];
            acc[t] = __builtin_amdgcn_mfma_f32_16x16x32_f16(wf, af[s], acc[t], 0, 0, 0);
        }
    }

    if (valid) {
        _Float16* Or = &Hout[(size_t)row * D + quad * 4];
        #pragma unroll
        for (int t = 0; t < 8; ++t) {
            half4 o;
            o[0] = (_Float16)acc[t][0]; o[1] = (_Float16)acc[t][1];
            o[2] = (_Float16)acc[t][2]; o[3] = (_Float16)acc[t][3];
            *(half4*)(Or + t * 16) = o;
        }
    }
}

// ============ fused: GEMM1 ∥ phase-A coarse binning ============
// Edge wall identified (r0/r2/r4/r9): scattered device atomics retire at
// ~14.5 G/s invariant under MLP/scope/footprint. Fix: LDS histogram over
// 782 coarse bins (dst>>7) + per-edge rank from LDS atomics (on-CU, fast);
// ONE global atomic per (block, nonzero bin) reserves space: ~305K global
// atomics total, 5.2x fewer. Writes land ~5-consecutive per bin per block
// -> L2-mergeable (unlike the old per-node scatter). GEMM blocks first so
// binning trickles in behind them (r1 lesson).

__launch_bounds__(256)
__global__ void k_fused1(const int* __restrict__ src, const int* __restrict__ dst,
                         int* __restrict__ coarseCnt, uint2* __restrict__ binned,
                         int E, int gblocks, int nbin,
                         const float* __restrict__ A, const _Float16* __restrict__ WT,
                         _Float16* __restrict__ Hout, int nrows) {
    __shared__ int lh[NBMAX];
    __shared__ int lb[NBMAX];
    if ((int)blockIdx.x < gblocks) {
        gemm_body<float>((int)blockIdx.x, A, WT, Hout, nrows);
        return;
    }
    const int t  = threadIdx.x;
    const int eb = ((int)blockIdx.x - gblocks) * EPB;

    for (int b = t; b < nbin; b += 256) lh[b] = 0;
    __syncthreads();

    int dv[16], sv[16], rv[16];
    #pragma unroll
    for (int k = 0; k < 16; ++k) {
        const int i = eb + k * 256 + t;
        dv[k] = -1;
        if (i < E) {
            dv[k] = dst[i];
            sv[k] = src[i];
            rv[k] = atomicAdd(&lh[dv[k] >> 7], 1);
        }
    }
    __syncthreads();

    for (int b = t; b < nbin; b += 256) {
        const int c = lh[b];
        lb[b] = (c > 0) ? atomicAdd(&coarseCnt[b], c) : 0;
    }
    __syncthreads();

    #pragma unroll
    for (int k = 0; k < 16; ++k) {
        if (dv[k] >= 0) {
            const int b   = dv[k] >> 7;
            const int pos = lb[b] + rv[k];
            if (pos < BCAP)
                binned[(size_t)b * BCAP + pos] = make_uint2((unsigned)dv[k], (unsigned)sv[k]);
        }
    }
}

// ============ k_scan: exclusive scan of coarse bin counts (1 block) ============

__global__ void k_scan(const int* __restrict__ coarseCnt, int* __restrict__ coarseOff,
                       int nbin) {
    __shared__ int v[NBMAX];
    const int t = threadIdx.x;
    for (int b = t; b < nbin; b += 256) v[b] = min(coarseCnt[b], BCAP);
    __syncthreads();
    if (t == 0) {
        int run = 0;
        for (int b = 0; b < nbin; ++b) { const int c = v[b]; v[b] = run; run += c; }
    }
    __syncthreads();
    for (int b = t; b < nbin; b += 256) coarseOff[b] = v[b];
}

// ============ k_binB: fine counting sort per coarse bin -> dense CSR ============
// One block per bin (<=2560 edges). 128-bin LDS histogram (dst&127) with
// rank capture, thread-0 prefix, contiguous epOut writes (block's whole
// output is one ~10KB dense range -> fully L2-merged). Emits cnt[] and
// offcnt[] = off | (deg<<21)  (off < E=1.6M < 2^21, deg clamped 127).
// Fixed 10-step unrolled local arrays: compile-time indexing only (no scratch).

__launch_bounds__(256)
__global__ void k_binB(const uint2* __restrict__ binned, const int* __restrict__ coarseCnt,
                       const int* __restrict__ coarseOff, int* __restrict__ epOut,
                       int* __restrict__ cnt, unsigned* __restrict__ offcnt, int n) {
    __shared__ int fh[128], pf[128];
    const int b = blockIdx.x;
    const int t = threadIdx.x;
    const int nb     = min(coarseCnt[b], BCAP);
    const int binOff = coarseOff[b];

    if (t < 128) fh[t] = 0;
    __syncthreads();

    int sv_[10], fv_[10], rv_[10];
    #pragma unroll
    for (int k = 0; k < 10; ++k) {
        const int j = t + k * 256;
        fv_[k] = -1;
        if (j < nb) {
            const uint2 p = binned[(size_t)b * BCAP + j];
            fv_[k] = (int)(p.x & 127u);
            sv_[k] = (int)p.y;
            rv_[k] = atomicAdd(&fh[fv_[k]], 1);
        }
    }
    __syncthreads();

    if (t == 0) {
        int run = 0;
        for (int f = 0; f < 128; ++f) { const int c = fh[f]; pf[f] = run; run += c; }
    }
    __syncthreads();

    #pragma unroll
    for (int k = 0; k < 10; ++k)
        if (fv_[k] >= 0) epOut[binOff + pf[fv_[k]] + rv_[k]] = sv_[k];

    if (t < 128) {
        const int node = b * 128 + t;
        if (node < n) {
            const int c = fh[t];
            cnt[node]    = c;
            offcnt[node] = (unsigned)(binOff + pf[t]) | ((unsigned)min(c, 127) << 21);
        }
    }
}

// ============ k_pack: embed cnt[src] into CSR entries (r8-proven format) ============
// epOut[i] = src | (min(cnt[src],4095)<<20); src < 2^17, mask 0xFFFFF exact.
// Dense E-array now (6.4MB) — cheaper than the old padded region.

__launch_bounds__(256)
__global__ void k_pack(int* __restrict__ epOut, const int* __restrict__ cnt, int E) {
    const int i = blockIdx.x * 256 + threadIdx.x;
    if (i < E) {
        const unsigned v = (unsigned)epOut[i];
        epOut[i] = (int)(v | ((unsigned)min(cnt[v], 4095) << 20));
    }
}

// ============ agg row: single-shfl packed gather+FMA over dense CSR ============
// r9-proven loop shape; base/deg from one offcnt load. Weights in exact f32
// from exact integer counts -> same numerics as all passing rounds.

template <int U>
__device__ __forceinline__ void grp(const _Float16* __restrict__ h, int c4,
                                    unsigned pv, float dd, int k, float4& acc) {
    unsigned p[U]; half4 v[U];
    #pragma unroll
    for (int u = 0; u < U; ++u) p[u] = __shfl(pv, k + u, 32);
    #pragma unroll
    for (int u = 0; u < U; ++u)
        v[u] = *(const half4*)&h[(size_t)(p[u] & 0xFFFFFu) * D + c4];
    #pragma unroll
    for (int u = 0; u < U; ++u) {
        const float w = rsqrtf(1.0f + (float)(p[u] >> 20)) * dd;
        acc.x = fmaf((float)v[u][0], w, acc.x);
        acc.y = fmaf((float)v[u][1], w, acc.y);
        acc.z = fmaf((float)v[u][2], w, acc.z);
        acc.w = fmaf((float)v[u][3], w, acc.w);
    }
}

__device__ __forceinline__ float4 agg_row(const _Float16* __restrict__ h,
                                          const unsigned* __restrict__ offcnt,
                                          const unsigned* __restrict__ ep,
                                          int row, int lane) {
    const int c4 = lane * 4;
    const unsigned oc = offcnt[row];
    const int base = (int)(oc & 0x1FFFFFu);
    const int cr   = (int)((oc >> 21) & 0x7Fu);
    const float dd = rsqrtf(1.0f + (float)cr);
    const float sw = dd * dd;
    const half4 hv = *(const half4*)&h[(size_t)row * D + c4];
    float4 acc = make_float4((float)hv[0] * sw, (float)hv[1] * sw,
                             (float)hv[2] * sw, (float)hv[3] * sw);

    for (int c = 0; c < cr; c += 32) {
        unsigned pv = 0;
        if (c + lane < cr) pv = ep[base + c + lane];
        const int m = min(32, cr - c);
        int k = 0;
        for (; k + 8 <= m; k += 8) grp<8>(h, c4, pv, dd, k, acc);
        for (; k + 4 <= m; k += 4) grp<4>(h, c4, pv, dd, k, acc);
        for (; k < m; ++k)         grp<1>(h, c4, pv, dd, k, acc);
    }
    return acc;
}

// ============ fused agg(layer1) + GEMM2: 32 rows / 128 threads ============

#define LSTRIDE 136  // _Float16 units (272 B row stride, 16B-aligned)

__launch_bounds__(128)
__global__ void k_agg_gemm2(const _Float16* __restrict__ h,
                            const unsigned* __restrict__ offcnt,
                            const unsigned* __restrict__ ep,
                            const float* __restrict__ bias, const _Float16* __restrict__ WT,
                            _Float16* __restrict__ Hout, int n) {
    __shared__ _Float16 sh[32 * LSTRIDE];

    const int r0   = blockIdx.x * 32;
    const int hw   = threadIdx.x >> 5;   // 0..3
    const int lane = threadIdx.x & 31;
    const int c4   = lane * 4;
    const float4 bb = *(const float4*)&bias[c4];

    #pragma unroll 1
    for (int i = 0; i < 8; ++i) {
        const int rl  = hw * 8 + i;
        const int row = r0 + rl;
        half4 o;
        if (row < n) {
            float4 acc = agg_row(h, offcnt, ep, row, lane);
            o[0] = (_Float16)fmaxf(acc.x + bb.x, 0.f);
            o[1] = (_Float16)fmaxf(acc.y + bb.y, 0.f);
            o[2] = (_Float16)fmaxf(acc.z + bb.z, 0.f);
            o[3] = (_Float16)fmaxf(acc.w + bb.w, 0.f);
        } else {
            o[0] = o[1] = o[2] = o[3] = (_Float16)0.f;
        }
        *(half4*)&sh[rl * LSTRIDE + c4] = o;
    }
    __syncthreads();

    const int wv   = threadIdx.x >> 6;   // 0..1
    const int wl64 = threadIdx.x & 63;
    const int l    = wl64 & 15;
    const int quad = wl64 >> 4;
    const int rl   = wv * 16 + l;
    const int row  = r0 + rl;

    half8 af[4];
    #pragma unroll
    for (int s = 0; s < 4; ++s)
        af[s] = *(const half8*)&sh[rl * LSTRIDE + s * 32 + quad * 8];

    f32x4 acc[8];
    #pragma unroll
    for (int t = 0; t < 8; ++t) acc[t] = (f32x4)0.0f;

    #pragma unroll
    for (int s = 0; s < 4; ++s) {
        #pragma unroll
        for (int t = 0; t < 8; ++t) {
            const half8 wf = *(const half8*)&WT[(size_t)(t * 16 + l) * D + s * 32 + quad * 8];
            acc[t] = __builtin_amdgcn_mfma_f32_16x16x32_f16(wf, af[s], acc[t], 0, 0, 0);
        }
    }

    if (row < n) {
        _Float16* Or = &Hout[(size_t)row * D + quad * 4];
        #pragma unroll
        for (int t = 0; t < 8; ++t) {
            half4 o;
            o[0] = (_Float16)acc[t][0]; o[1] = (_Float16)acc[t][1];
            o[2] = (_Float16)acc[t][2]; o[3] = (_Float16)acc[t][3];
            *(half4*)(Or + t * 16) = o;
        }
    }
}

// ============ final agg (layer2) -> fp32 d_out: 8 rows / 256 thr ============

__launch_bounds__(256)
__global__ void k_agg_out(const _Float16* __restrict__ h,
                          const unsigned* __restrict__ offcnt,
                          const unsigned* __restrict__ ep,
                          const float* __restrict__ bias, float* __restrict__ out, int n) {
    const int row = blockIdx.x * 8 + (threadIdx.x >> 5);
    if (row >= n) return;
    const int lane = threadIdx.x & 31;
    const int c4 = lane * 4;
    const float4 bb = *(const float4*)&bias[c4];

    float4 acc = agg_row(h, offcnt, ep, row, lane);
    acc.x = fmaxf(acc.x + bb.x, 0.f);
    acc.y = fmaxf(acc.y + bb.y, 0.f);
    acc.z = fmaxf(acc.z + bb.z, 0.f);
    acc.w = fmaxf(acc.w + bb.w, 0.f);
    *(float4*)&out[(size_t)row * D + c4] = acc;
}

// ================= launch =================

extern "C" void kernel_launch(void* const* d_in, const int* in_sizes, int n_in,
                              void* d_out, int out_size, void* d_ws, size_t ws_size,
                              hipStream_t stream) {
    const float* x  = (const float*)d_in[0];
    const int*   ei = (const int*)d_in[1];
    const float* W1 = (const float*)d_in[2];
    const float* b1 = (const float*)d_in[3];
    const float* W2 = (const float*)d_in[4];
    const float* b2 = (const float*)d_in[5];

    const int N = in_sizes[0] / D;     // 100000
    const int E = in_sizes[1] / 2;     // 1600000
    const int* src = ei;
    const int* dst = ei + E;
    float* out = (float*)d_out;

    const int nbin = (N + 127) / 128;  // 782 (<= NBMAX)

    auto align256 = [](size_t v) { return (v + 255) & ~(size_t)255; };
    char* w = (char*)d_ws;
    int*      cnt       = (int*)w;      w += align256((size_t)N * 4);
    unsigned* offcnt    = (unsigned*)w; w += align256((size_t)N * 4);
    int*      coarseCnt = (int*)w;      w += align256((size_t)nbin * 4);
    int*      coarseOff = (int*)w;      w += align256((size_t)nbin * 4);
    _Float16* WT1       = (_Float16*)w; w += align256((size_t)D * D * 2);
    _Float16* WT2       = (_Float16*)w; w += align256((size_t)D * D * 2);
    uint2*    binned    = (uint2*)w;    w += align256((size_t)nbin * BCAP * 8); // 16.0 MB
    int*      epOut     = (int*)w;      w += align256((size_t)E * 4);           // 6.4 MB
    _Float16* hA        = (_Float16*)w; w += align256((size_t)N * D * 2);       // 25.6 MB
    _Float16* hB        = (_Float16*)w;
    // total ~74.5 MB — under the proven 77 MB footprint

    const int abgrid = (E + EPB - 1) / EPB;   // 391 phase-A blocks
    const int ggrid  = (N + 63) / 64;         // 1563 GEMM blocks

    hipMemsetAsync(coarseCnt, 0, (size_t)nbin * 4, stream);
    k_prepW2<<<(2 * D * D + 255) / 256, 256, 0, stream>>>(W1, W2, WT1, WT2);

    // GEMM1 (-> fp16 hA) first; coarse binning trickles in behind (overlap)
    k_fused1<<<ggrid + abgrid, 256, 0, stream>>>(src, dst, coarseCnt, binned, E, ggrid,
                                                 nbin, x, WT1, hA, N);

    // exclusive scan of 782 coarse counts (1 block, ~3us)
    k_scan<<<1, 256, 0, stream>>>(coarseCnt, coarseOff, nbin);

    // fine counting sort per bin -> dense CSR + cnt + offcnt (~10us)
    k_binB<<<nbin, 256, 0, stream>>>(binned, coarseCnt, coarseOff, epOut, cnt, offcnt, N);

    // embed cnt[src] into CSR entries (~8us)
    k_pack<<<(E + 255) / 256, 256, 0, stream>>>(epOut, cnt, E);

    // agg(layer1) + GEMM2 fused, 32 rows/block
    k_agg_gemm2<<<(N + 31) / 32, 128, 0, stream>>>(hA, offcnt, (const unsigned*)epOut,
                                                   b1, WT2, hB, N);

    // final aggregation -> d_out
    k_agg_out<<<(N + 7) / 8, 256, 0, stream>>>(hB, offcnt, (const unsigned*)epOut,
                                               b2, out, N);
}

// Round 11
// 337.078 us; speedup vs baseline: 1.1671x; 1.0029x over previous
//
#include <hip/hip_runtime.h>
#include <hip/hip_bf16.h>
#include <hip/hip_fp16.h>

#define D 128
#define EPB 4096      // edges per phase-A block (256 thr x 16)
#define NBMAX 784     // max coarse bins (ceil(100000/128)=782)
#define BCAP 2560     // per-coarse-bin capacity: Poisson(2048) + 11 sigma

typedef _Float16 half8 __attribute__((ext_vector_type(8)));
typedef _Float16 half4 __attribute__((ext_vector_type(4)));
typedef float f32x4 __attribute__((ext_vector_type(4)));
typedef float f32x8 __attribute__((ext_vector_type(8)));

// ============ W prep: WT[n][k] = (fp16) W[k][n], both weights ============

__global__ void k_prepW2(const float* __restrict__ W1, const float* __restrict__ W2,
                         _Float16* __restrict__ WT1, _Float16* __restrict__ WT2) {
    const int i = blockIdx.x * 256 + threadIdx.x;
    if (i < 2 * D * D) {
        const float* W = (i < D * D) ? W1 : W2;
        _Float16* WT   = (i < D * D) ? WT1 : WT2;
        const int j = (i < D * D) ? i : i - D * D;
        const int k = j >> 7, n = j & 127;
        WT[n * D + k] = (_Float16)W[j];
    }
}

// ============ GEMM body (A from global), fp16 out ============

template <typename AT>
__device__ __forceinline__ void gemm_body(int bid, const AT* __restrict__ A,
                                          const _Float16* __restrict__ WT,
                                          _Float16* __restrict__ Hout, int nrows) {
    const int wv   = threadIdx.x >> 6;
    const int lane = threadIdx.x & 63;
    const int l    = lane & 15;
    const int quad = lane >> 4;
    const int base = bid * 64 + wv * 16;
    int row = base + l;
    const bool valid = row < nrows;
    if (!valid) row = nrows - 1;

    half8 af[4];
    const AT* Ar = &A[(size_t)row * D + quad * 8];
    #pragma unroll
    for (int s = 0; s < 4; ++s) {
        if constexpr (sizeof(AT) == 4) {
            const float4 v0 = *(const float4*)(Ar + s * 32);
            const float4 v1 = *(const float4*)(Ar + s * 32 + 4);
            af[s][0] = (_Float16)v0.x; af[s][1] = (_Float16)v0.y;
            af[s][2] = (_Float16)v0.z; af[s][3] = (_Float16)v0.w;
            af[s][4] = (_Float16)v1.x; af[s][5] = (_Float16)v1.y;
            af[s][6] = (_Float16)v1.z; af[s][7] = (_Float16)v1.w;
        } else {
            af[s] = *(const half8*)(Ar + s * 32);
        }
    }

    f32x4 acc[8];
    #pragma unroll
    for (int t = 0; t < 8; ++t) acc[t] = (f32x4)0.0f;

    #pragma unroll
    for (int s = 0; s < 4; ++s) {
        #pragma unroll
        for (int t = 0; t < 8; ++t) {
            const half8 wf = *(const half8*)&WT[(size_t)(t * 16 + l) * D + s * 32 + quad * 8];
            acc[t] = __builtin_amdgcn_mfma_f32_16x16x32_f16(wf, af[s], acc[t], 0, 0, 0);
        }
    }

    if (valid) {
        _Float16* Or = &Hout[(size_t)row * D + quad * 4];
        #pragma unroll
        for (int t = 0; t < 8; ++t) {
            half4 o;
            o[0] = (_Float16)acc[t][0]; o[1] = (_Float16)acc[t][1];
            o[2] = (_Float16)acc[t][2]; o[3] = (_Float16)acc[t][3];
            *(half4*)(Or + t * 16) = o;
        }
    }
}

// ============ fused: GEMM1 ∥ phase-A coarse binning (r10-proven) ============
// LDS histogram over 782 coarse bins (dst>>7) + per-edge rank; one global
// atomic per (block, nonzero bin) ~ 305K total (vs 1.6M; the 14.5 G/s
// scattered-atomic wall from r0-r9 is gone). GEMM blocks first (r1 lesson).

__launch_bounds__(256)
__global__ void k_fused1(const int* __restrict__ src, const int* __restrict__ dst,
                         int* __restrict__ coarseCnt, uint2* __restrict__ binned,
                         int E, int gblocks, int nbin,
                         const float* __restrict__ A, const _Float16* __restrict__ WT,
                         _Float16* __restrict__ Hout, int nrows) {
    __shared__ int lh[NBMAX];
    __shared__ int lb[NBMAX];
    if ((int)blockIdx.x < gblocks) {
        gemm_body<float>((int)blockIdx.x, A, WT, Hout, nrows);
        return;
    }
    const int t  = threadIdx.x;
    const int eb = ((int)blockIdx.x - gblocks) * EPB;

    for (int b = t; b < nbin; b += 256) lh[b] = 0;
    __syncthreads();

    int dv[16], sv[16], rv[16];
    #pragma unroll
    for (int k = 0; k < 16; ++k) {
        const int i = eb + k * 256 + t;
        dv[k] = -1;
        if (i < E) {
            dv[k] = dst[i];
            sv[k] = src[i];
            rv[k] = atomicAdd(&lh[dv[k] >> 7], 1);
        }
    }
    __syncthreads();

    for (int b = t; b < nbin; b += 256) {
        const int c = lh[b];
        lb[b] = (c > 0) ? atomicAdd(&coarseCnt[b], c) : 0;
    }
    __syncthreads();

    #pragma unroll
    for (int k = 0; k < 16; ++k) {
        if (dv[k] >= 0) {
            const int b   = dv[k] >> 7;
            const int pos = lb[b] + rv[k];
            if (pos < BCAP)
                binned[(size_t)b * BCAP + pos] = make_uint2((unsigned)dv[k], (unsigned)sv[k]);
        }
    }
}

// ============ k_binB: fine counting sort -> dense CSR (self-allocating) ============
// k_scan removed: each block reserves its output range with ONE atomic on a
// global allocator (782 total). Base relocation doesn't change within-segment
// neighbor order -> numerics identical. offcnt = off | (deg<<21).

__launch_bounds__(256)
__global__ void k_binB(const uint2* __restrict__ binned, const int* __restrict__ coarseCnt,
                       int* __restrict__ allocTot, int* __restrict__ epOut,
                       int* __restrict__ cnt, unsigned* __restrict__ offcnt, int n) {
    __shared__ int fh[128], pf[128];
    __shared__ int sOff;
    const int b = blockIdx.x;
    const int t = threadIdx.x;
    const int nb = min(coarseCnt[b], BCAP);
    if (t == 0) sOff = atomicAdd(allocTot, nb);

    if (t < 128) fh[t] = 0;
    __syncthreads();

    int sv_[10], fv_[10], rv_[10];
    #pragma unroll
    for (int k = 0; k < 10; ++k) {
        const int j = t + k * 256;
        fv_[k] = -1;
        if (j < nb) {
            const uint2 p = binned[(size_t)b * BCAP + j];
            fv_[k] = (int)(p.x & 127u);
            sv_[k] = (int)p.y;
            rv_[k] = atomicAdd(&fh[fv_[k]], 1);
        }
    }
    __syncthreads();

    if (t == 0) {
        int run = 0;
        for (int f = 0; f < 128; ++f) { const int c = fh[f]; pf[f] = run; run += c; }
    }
    __syncthreads();

    const int binOff = sOff;
    #pragma unroll
    for (int k = 0; k < 10; ++k)
        if (fv_[k] >= 0) epOut[binOff + pf[fv_[k]] + rv_[k]] = sv_[k];

    if (t < 128) {
        const int node = b * 128 + t;
        if (node < n) {
            const int c = fh[t];
            cnt[node]    = c;
            offcnt[node] = (unsigned)(binOff + pf[t]) | ((unsigned)min(c, 127) << 21);
        }
    }
}

// ============ k_pack: embed cnt[src] into CSR entries ============
// epOut[i] = src | (min(cnt[src],4095)<<20); guarded by the allocator total.

__launch_bounds__(256)
__global__ void k_pack(int* __restrict__ epOut, const int* __restrict__ cnt,
                       const int* __restrict__ allocTot) {
    const int tot = *allocTot;
    const int i = blockIdx.x * 256 + threadIdx.x;
    if (i < tot) {
        const unsigned v = (unsigned)epOut[i];
        epOut[i] = (int)(v | ((unsigned)min(cnt[v & 0xFFFFF], 4095) << 20));
    }
}

// ============ agg row: DUAL-NEIGHBOR half8 gathers ============
// r10 diagnosis: agg is issue/concurrency-limited (2.4 TB/s fill << ceilings,
// VALU 34%, MFMA idle). Fix: lanes 0-15 fetch half8 of neighbor k, lanes
// 16-31 of neighbor k+1 -> per neighbor: VMEM x1/2, shfl x1/2, rsqrt x1/2,
// addr-calc x1/2; rows in flight per group x2. Same bytes, same FLOPs.
// Halves combined by one shfl_xor(16) per accumulator; self term added after
// (avoids double count). Weights exact f32 from exact integer counts.

template <int U>
__device__ __forceinline__ void grp2(const _Float16* __restrict__ h, int l8, int hh,
                                     unsigned pv, float dd, int k, int m, f32x8& acc) {
    unsigned p[U]; half8 v[U];
    #pragma unroll
    for (int u = 0; u < U; ++u)
        p[u] = __shfl(pv, k + 2 * u + hh, 32);
    #pragma unroll
    for (int u = 0; u < U; ++u)
        v[u] = *(const half8*)&h[(size_t)(p[u] & 0xFFFFFu) * D + l8];
    #pragma unroll
    for (int u = 0; u < U; ++u) {
        const float w = (k + 2 * u + hh < m)
                      ? rsqrtf(1.0f + (float)(p[u] >> 20)) * dd : 0.0f;
        #pragma unroll
        for (int j = 0; j < 8; ++j)
            acc[j] = fmaf((float)v[u][j], w, acc[j]);
    }
}

__device__ __forceinline__ f32x8 agg_row8(const _Float16* __restrict__ h,
                                          const unsigned* __restrict__ offcnt,
                                          const unsigned* __restrict__ ep,
                                          int row, int lane) {
    const int l8 = (lane & 15) * 8;
    const int hh = lane >> 4;            // 0: even neighbors, 1: odd neighbors
    const unsigned oc = offcnt[row];
    const int base = (int)(oc & 0x1FFFFFu);
    const int cr   = (int)((oc >> 21) & 0x7Fu);
    const float dd = rsqrtf(1.0f + (float)cr);
    const float sw = dd * dd;
    f32x8 acc = (f32x8)0.0f;

    for (int c = 0; c < cr; c += 32) {
        unsigned pv = 0;
        if (c + lane < cr) pv = ep[base + c + lane];
        const int m = min(32, cr - c);
        int k = 0;
        for (; k + 8 <= m; k += 8) grp2<4>(h, l8, hh, pv, dd, k, m, acc);
        for (; k < m; k += 2)      grp2<1>(h, l8, hh, pv, dd, k, m, acc);
    }

    #pragma unroll
    for (int j = 0; j < 8; ++j) acc[j] += __shfl_xor(acc[j], 16, 32);

    const half8 hv = *(const half8*)&h[(size_t)row * D + l8];
    #pragma unroll
    for (int j = 0; j < 8; ++j) acc[j] = fmaf((float)hv[j], sw, acc[j]);
    return acc;
}

// ============ fused agg(layer1) + GEMM2: 32 rows / 128 threads ============

#define LSTRIDE 136  // _Float16 units (272 B row stride, 16B-aligned)

__launch_bounds__(128)
__global__ void k_agg_gemm2(const _Float16* __restrict__ h,
                            const unsigned* __restrict__ offcnt,
                            const unsigned* __restrict__ ep,
                            const float* __restrict__ bias, const _Float16* __restrict__ WT,
                            _Float16* __restrict__ Hout, int n) {
    __shared__ _Float16 sh[32 * LSTRIDE];

    const int r0   = blockIdx.x * 32;
    const int hw   = threadIdx.x >> 5;   // 0..3
    const int lane = threadIdx.x & 31;
    const int l8   = (lane & 15) * 8;
    const int hh   = lane >> 4;
    const float4 bb0 = *(const float4*)&bias[l8];
    const float4 bb1 = *(const float4*)&bias[l8 + 4];

    #pragma unroll 1
    for (int i = 0; i < 8; ++i) {
        const int rl  = hw * 8 + i;
        const int row = r0 + rl;
        half8 o;
        if (row < n) {
            f32x8 a = agg_row8(h, offcnt, ep, row, lane);
            o[0] = (_Float16)fmaxf(a[0] + bb0.x, 0.f);
            o[1] = (_Float16)fmaxf(a[1] + bb0.y, 0.f);
            o[2] = (_Float16)fmaxf(a[2] + bb0.z, 0.f);
            o[3] = (_Float16)fmaxf(a[3] + bb0.w, 0.f);
            o[4] = (_Float16)fmaxf(a[4] + bb1.x, 0.f);
            o[5] = (_Float16)fmaxf(a[5] + bb1.y, 0.f);
            o[6] = (_Float16)fmaxf(a[6] + bb1.z, 0.f);
            o[7] = (_Float16)fmaxf(a[7] + bb1.w, 0.f);
        } else {
            #pragma unroll
            for (int j = 0; j < 8; ++j) o[j] = (_Float16)0.f;
        }
        if (hh == 0) *(half8*)&sh[rl * LSTRIDE + l8] = o;
    }
    __syncthreads();

    const int wv   = threadIdx.x >> 6;   // 0..1
    const int wl64 = threadIdx.x & 63;
    const int l    = wl64 & 15;
    const int quad = wl64 >> 4;
    const int rl   = wv * 16 + l;
    const int row  = r0 + rl;

    half8 af[4];
    #pragma unroll
    for (int s = 0; s < 4; ++s)
        af[s] = *(const half8*)&sh[rl * LSTRIDE + s * 32 + quad * 8];

    f32x4 acc[8];
    #pragma unroll
    for (int t = 0; t < 8; ++t) acc[t] = (f32x4)0.0f;

    #pragma unroll
    for (int s = 0; s < 4; ++s) {
        #pragma unroll
        for (int t = 0; t < 8; ++t) {
            const half8 wf = *(const half8*)&WT[(size_t)(t * 16 + l) * D + s * 32 + quad * 8];
            acc[t] = __builtin_amdgcn_mfma_f32_16x16x32_f16(wf, af[s], acc[t], 0, 0, 0);
        }
    }

    if (row < n) {
        _Float16* Or = &Hout[(size_t)row * D + quad * 4];
        #pragma unroll
        for (int t = 0; t < 8; ++t) {
            half4 o;
            o[0] = (_Float16)acc[t][0]; o[1] = (_Float16)acc[t][1];
            o[2] = (_Float16)acc[t][2]; o[3] = (_Float16)acc[t][3];
            *(half4*)(Or + t * 16) = o;
        }
    }
}

// ============ final agg (layer2) -> fp32 d_out: 8 rows / 256 thr ============

__launch_bounds__(256)
__global__ void k_agg_out(const _Float16* __restrict__ h,
                          const unsigned* __restrict__ offcnt,
                          const unsigned* __restrict__ ep,
                          const float* __restrict__ bias, float* __restrict__ out, int n) {
    const int row = blockIdx.x * 8 + (threadIdx.x >> 5);
    if (row >= n) return;
    const int lane = threadIdx.x & 31;
    const int l8   = (lane & 15) * 8;
    const int hh   = lane >> 4;
    const float4 bb0 = *(const float4*)&bias[l8];
    const float4 bb1 = *(const float4*)&bias[l8 + 4];

    f32x8 a = agg_row8(h, offcnt, ep, row, lane);
    if (hh == 0) {
        float4 o0 = make_float4(fmaxf(a[0] + bb0.x, 0.f), fmaxf(a[1] + bb0.y, 0.f),
                                fmaxf(a[2] + bb0.z, 0.f), fmaxf(a[3] + bb0.w, 0.f));
        float4 o1 = make_float4(fmaxf(a[4] + bb1.x, 0.f), fmaxf(a[5] + bb1.y, 0.f),
                                fmaxf(a[6] + bb1.z, 0.f), fmaxf(a[7] + bb1.w, 0.f));
        *(float4*)&out[(size_t)row * D + l8]     = o0;
        *(float4*)&out[(size_t)row * D + l8 + 4] = o1;
    }
}

// ================= launch =================

extern "C" void kernel_launch(void* const* d_in, const int* in_sizes, int n_in,
                              void* d_out, int out_size, void* d_ws, size_t ws_size,
                              hipStream_t stream) {
    const float* x  = (const float*)d_in[0];
    const int*   ei = (const int*)d_in[1];
    const float* W1 = (const float*)d_in[2];
    const float* b1 = (const float*)d_in[3];
    const float* W2 = (const float*)d_in[4];
    const float* b2 = (const float*)d_in[5];

    const int N = in_sizes[0] / D;     // 100000
    const int E = in_sizes[1] / 2;     // 1600000
    const int* src = ei;
    const int* dst = ei + E;
    float* out = (float*)d_out;

    const int nbin = (N + 127) / 128;  // 782 (<= NBMAX)

    auto align256 = [](size_t v) { return (v + 255) & ~(size_t)255; };
    char* w = (char*)d_ws;
    int*      cnt       = (int*)w;      w += align256((size_t)N * 4);
    unsigned* offcnt    = (unsigned*)w; w += align256((size_t)N * 4);
    int*      coarseCnt = (int*)w;      w += align256((size_t)(nbin + 1) * 4);
    int*      allocTot  = coarseCnt + nbin;   // one extra int, memset together
    _Float16* WT1       = (_Float16*)w; w += align256((size_t)D * D * 2);
    _Float16* WT2       = (_Float16*)w; w += align256((size_t)D * D * 2);
    uint2*    binned    = (uint2*)w;    w += align256((size_t)nbin * BCAP * 8); // 16.0 MB
    int*      epOut     = (int*)w;      w += align256((size_t)E * 4);           // 6.4 MB
    _Float16* hA        = (_Float16*)w; w += align256((size_t)N * D * 2);       // 25.6 MB
    _Float16* hB        = (_Float16*)w;
    // total ~74.5 MB — under the proven 77 MB footprint

    const int abgrid = (E + EPB - 1) / EPB;   // 391 phase-A blocks
    const int ggrid  = (N + 63) / 64;         // 1563 GEMM blocks

    hipMemsetAsync(coarseCnt, 0, (size_t)(nbin + 1) * 4, stream);
    k_prepW2<<<(2 * D * D + 255) / 256, 256, 0, stream>>>(W1, W2, WT1, WT2);

    // GEMM1 (-> fp16 hA) first; coarse binning trickles in behind (overlap)
    k_fused1<<<ggrid + abgrid, 256, 0, stream>>>(src, dst, coarseCnt, binned, E, ggrid,
                                                 nbin, x, WT1, hA, N);

    // fine counting sort per bin -> dense CSR + cnt + offcnt (self-allocating)
    k_binB<<<nbin, 256, 0, stream>>>(binned, coarseCnt, allocTot, epOut, cnt, offcnt, N);

    // embed cnt[src] into CSR entries
    k_pack<<<(E + 255) / 256, 256, 0, stream>>>(epOut, cnt, allocTot);

    // agg(layer1) + GEMM2 fused, 32 rows/block, dual-neighbor gathers
    k_agg_gemm2<<<(N + 31) / 32, 128, 0, stream>>>(hA, offcnt, (const unsigned*)epOut,
                                                   b1, WT2, hB, N);

    // final aggregation -> d_out, dual-neighbor gathers
    k_agg_out<<<(N + 7) / 8, 256, 0, stream>>>(hB, offcnt, (const unsigned*)epOut,
                                               b2, out, N);
}